// Round 9
// baseline (316.615 us; speedup 1.0000x reference)
//
#include <hip/hip_runtime.h>
#include <hip/hip_bf16.h>
#include <float.h>

// B=4, S=2048, D=1024 causal attention with input projections.
// out = softmax(mask((q@Wq)(k@Wk)^T / 32)) @ (v@Wv)
//
// Numerics: logits std ~342 -> q/k path uses bf16x2 (hi/lo RTN) split
// arithmetic, ~2^-18 effective. RTN mandatory (R2 lesson). v path bf16.
//
// R9: proj_qk rebuilt as 256x256-tile 8-phase pipelined GEMM (T2+T3+T4+T5)
// with K'=3072 = [Ah.Bh | Al.Bh | Ah.Bl] segment concatenation (the 3-MFMA
// split as one plain bf16 GEMM). 8 waves, 2 LDS K-tile slots (128 KB),
// counted vmcnt(4), raw asm barriers, st-swizzle col^=((row>>2)&3)<<5 on
// both stage-source and ds_read. Everything else unchanged from R8.

typedef __attribute__((ext_vector_type(8))) short bf16x8;
typedef __attribute__((ext_vector_type(4))) float f32x4;

#define MFMA16 __builtin_amdgcn_mfma_f32_16x16x32_bf16

union U8 { bf16x8 v; unsigned w[4]; };

__device__ __forceinline__ ushort f2bf(float x) {
  union { float f; unsigned u; } v; v.f = x;
  unsigned r = v.u + 0x7fffu + ((v.u >> 16) & 1u);
  return (ushort)(r >> 16);
}
__device__ __forceinline__ float bf2f(ushort h) {
  union { unsigned u; float f; } v; v.u = ((unsigned)h) << 16;
  return v.f;
}
__device__ __forceinline__ void splitf(float x, ushort& hi, ushort& lo) {
  hi = f2bf(x);
  lo = f2bf(x - bf2f(hi));
}

__device__ __forceinline__ bf16x8 cvt8(const float* lp) {
  U8 H;
#pragma unroll
  for (int p = 0; p < 4; ++p) {
    const unsigned u0 = __float_as_uint(lp[2 * p]);
    const unsigned u1 = __float_as_uint(lp[2 * p + 1]);
    const unsigned r0 = (u0 + 0x7fffu + ((u0 >> 16) & 1u)) >> 16;
    const unsigned r1 = (u1 + 0x7fffu + ((u1 >> 16) & 1u)) & 0xffff0000u;
    H.w[p] = r0 | r1;
  }
  return H.v;
}

#define GLOAD16(gp, lp)                                                        \
  __builtin_amdgcn_global_load_lds(                                            \
      (const __attribute__((address_space(1))) void*)(gp),                     \
      (__attribute__((address_space(3))) void*)(lp), 16, 0, 0)

#define BARRIER() asm volatile("s_barrier" ::: "memory")
#define VMCNT4() asm volatile("s_waitcnt vmcnt(4)" ::: "memory")

// bf16 slab 128 x 32 (8 KB, 8 chunks)
__device__ __forceinline__ void stage_bf16_32(const ushort* g, int pitch,
                                              ushort* lds, int w, int lane) {
#pragma unroll
  for (int i = 0; i < 2; ++i) {
    const int c = w * 2 + i;
    const int row = c * 16 + (lane >> 2);
    const int kp = (lane & 3) * 8;
    GLOAD16(g + (size_t)row * pitch + kp, lds + c * 512);
  }
}
// bf16 slab 128 x 64 (16 KB, 16 chunks)
__device__ __forceinline__ void stage_bf16_64(const ushort* g, int pitch,
                                              ushort* lds, int w, int lane) {
#pragma unroll
  for (int i = 0; i < 4; ++i) {
    const int c = w * 4 + i;
    const int row = c * 8 + (lane >> 3);
    const int kp = (lane & 7) * 8;
    GLOAD16(g + (size_t)row * pitch + kp, lds + c * 512);
  }
}
// bf16 slab 64 x 64 (8 KB, 8 chunks)
__device__ __forceinline__ void stage_bf16_64x64(const ushort* g, int pitch,
                                                 ushort* lds, int w, int lane) {
#pragma unroll
  for (int i = 0; i < 2; ++i) {
    const int c = w * 2 + i;
    const int row = c * 8 + (lane >> 3);
    const int kp = (lane & 7) * 8;
    GLOAD16(g + (size_t)row * pitch + kp, lds + c * 512);
  }
}
// fp32 slab 128 x 32 (16 KB, 16 chunks)
__device__ __forceinline__ void stage_f32_32(const float* g, int pitch,
                                             float* lds, int w, int lane) {
#pragma unroll
  for (int i = 0; i < 4; ++i) {
    const int c = w * 4 + i;
    const int row = c * 8 + (lane >> 3);
    const int kp = (lane & 7) * 4;
    GLOAD16(g + (size_t)row * pitch + kp, lds + c * 256);
  }
}

// Half-tile stage for proj_qk8: 128 rows x 64 cols bf16 (16 KB, 1024 chunks,
// 512 threads x 2). Linear LDS dest (base + lane*16B); swizzle realized by
// XORing the SOURCE column byte (rule #21: inverse-swz source + swz read).
__device__ __forceinline__ void stage_half8(const ushort* __restrict__ g,
                                            ushort* lds, int k0, int t) {
#pragma unroll
  for (int i = 0; i < 2; ++i) {
    const int c = t + i * 512;
    const int row = c >> 3;
    const int pcb = (c & 7) * 16;
    const int lcb = pcb ^ (((row >> 2) & 3) << 5);
    GLOAD16(g + (size_t)row * 1024 + k0 + (lcb >> 1), lds + c * 8);
  }
}

// ---------------------------------------------------------------------------
// Merged prepass: f < 3072 -> W transpose+convert; f >= 3072 -> q/k split.
// ---------------------------------------------------------------------------
__global__ __launch_bounds__(256) void wt_split(
    const float* __restrict__ q, const float* __restrict__ k,
    const float* __restrict__ W0, const float* __restrict__ W1,
    const float* __restrict__ W2, ushort* __restrict__ Th0,
    ushort* __restrict__ Tl0, ushort* __restrict__ Th1,
    ushort* __restrict__ Tl1, ushort* __restrict__ Th2,
    ushort* __restrict__ qh, ushort* __restrict__ ql,
    ushort* __restrict__ kh, ushort* __restrict__ kl) {
  __shared__ float t[32][33];
  const int f = blockIdx.x;
  if (f < 3072) {
    const int z = f >> 10, r10 = f & 1023;
    const int bx = r10 & 31, by = r10 >> 5;
    const float* W = z == 0 ? W0 : (z == 1 ? W1 : W2);
    ushort* Th = z == 0 ? Th0 : (z == 1 ? Th1 : Th2);
    ushort* Tl = z == 0 ? Tl0 : (z == 1 ? Tl1 : nullptr);
    const int r = threadIdx.x >> 3, c4 = (threadIdx.x & 7) * 4;
    const float4 x = *reinterpret_cast<const float4*>(
        &W[(size_t)(bx * 32 + r) * 1024 + by * 32 + c4]);
    t[r][c4] = x.x; t[r][c4 + 1] = x.y; t[r][c4 + 2] = x.z; t[r][c4 + 3] = x.w;
    __syncthreads();
    ushort h[4], l[4];
#pragma unroll
    for (int j = 0; j < 4; ++j) splitf(t[c4 + j][r], h[j], l[j]);
    const size_t o = (size_t)(by * 32 + r) * 1024 + bx * 32 + c4;
    *reinterpret_cast<ushort4*>(&Th[o]) = ushort4{h[0], h[1], h[2], h[3]};
    if (Tl)
      *reinterpret_cast<ushort4*>(&Tl[o]) = ushort4{l[0], l[1], l[2], l[3]};
  } else {
    const int fl = f - 3072;
    const float* X = (fl >> 11) ? k : q;
    ushort* H = (fl >> 11) ? kh : qh;
    ushort* L = (fl >> 11) ? kl : ql;
    const int n4 = 2097152;
    for (int i = (fl & 2047) * 256 + threadIdx.x; i < n4; i += 2048 * 256) {
      const float4 x = reinterpret_cast<const float4*>(X)[i];
      ushort h0, l0, h1, l1, h2, l2, h3, l3;
      splitf(x.x, h0, l0); splitf(x.y, h1, l1);
      splitf(x.z, h2, l2); splitf(x.w, h3, l3);
      reinterpret_cast<ushort4*>(H)[i] = ushort4{h0, h1, h2, h3};
      reinterpret_cast<ushort4*>(L)[i] = ushort4{l0, l1, l2, l3};
    }
  }
}

// ---------------------------------------------------------------------------
// proj_qk8: O = A @ Wt^T as one bf16 GEMM, K' = 3072 segments
// [Ah.Bh | Al.Bh | Ah.Bl]. 256x256 tile, BK=64, 8 waves (2Mx4N), 8-phase
// schedule, 2 K-tile LDS slots (slot = kt&1), counted vmcnt(4) at p0/p4.
// Grid 256 (z:2 x yt:32 x xt:4), bijective XCD chunk swizzle.
// ---------------------------------------------------------------------------
__global__ __launch_bounds__(512, 2) void proj_qk8(
    const ushort* __restrict__ Ah0, const ushort* __restrict__ Al0,
    const ushort* __restrict__ Ah1, const ushort* __restrict__ Al1,
    const ushort* __restrict__ Bh0, const ushort* __restrict__ Bl0,
    const ushort* __restrict__ Bh1, const ushort* __restrict__ Bl1,
    ushort* __restrict__ Oh0, ushort* __restrict__ Ol0,
    ushort* __restrict__ Oh1, ushort* __restrict__ Ol1) {
  __shared__ ushort As[2][16384];  // [slot][256 rows x 64 cols], 64 KB
  __shared__ ushort Bs[2][16384];  // 64 KB
  const int bid = blockIdx.x;
  const int fid = (bid & 7) * 32 + (bid >> 3);  // 256 blocks, 8 XCDs: chunked
  const int z = fid >> 7, r = fid & 127;
  const int yt = r >> 2, xt = r & 3;
  const ushort* Ah = z ? Ah1 : Ah0;
  const ushort* Al = z ? Al1 : Al0;
  const ushort* Bh = z ? Bh1 : Bh0;
  const ushort* Bl = z ? Bl1 : Bl0;
  ushort* Oh = z ? Oh1 : Oh0;
  ushort* Ol = z ? Ol1 : Ol0;
  const size_t am0 = (size_t)yt * 256 * 1024;
  const size_t bn0 = (size_t)xt * 256 * 1024;
  const int t = threadIdx.x;
  const int lane = t & 63, w = t >> 6;
  const int wm = w >> 2, wn = w & 3;
  const int lr = lane & 15, kg = lane >> 4;
  f32x4 acc[8][4] = {};
  bf16x8 Ar[4][2], Br[4][2];

  // stage unit u of K-tile kt: u 0/1 = A half0/1, 2/3 = B half0/1.
  auto stage_unit = [&](int kt, int u) {
    if (kt >= 48) kt -= 48;  // wrap: harmless dummy re-stage (uniform vmcnt)
    const int seg = kt >> 4;
    const int k0 = (kt & 15) * 64;
    const int slot = kt & 1;
    const int h = u & 1;
    if (u < 2) {
      const ushort* g = ((seg == 1) ? Al : Ah) + am0 + (size_t)(h * 128) * 1024;
      stage_half8(g, &As[slot][h * 8192], k0, t);
    } else {
      const ushort* g = ((seg == 2) ? Bl : Bh) + bn0 + (size_t)(h * 128) * 1024;
      stage_half8(g, &Bs[slot][h * 8192], k0, t);
    }
  };
  auto loadA = [&](int slot, int mq) {
#pragma unroll
    for (int m = 0; m < 4; ++m)
#pragma unroll
      for (int ks = 0; ks < 2; ++ks) {
        const int row = wm * 128 + (mq * 4 + m) * 16 + lr;
        const int cb = (ks * 64 + kg * 16) ^ (((row >> 2) & 3) << 5);
        Ar[m][ks] =
            *reinterpret_cast<const bf16x8*>(&As[slot][row * 64 + (cb >> 1)]);
      }
  };
  auto loadB = [&](int slot, int nq) {
#pragma unroll
    for (int n = 0; n < 2; ++n)
#pragma unroll
      for (int ks = 0; ks < 2; ++ks) {
        const int col = wn * 64 + (nq * 2 + n) * 16 + lr;
        const int cb = (ks * 64 + kg * 16) ^ (((col >> 2) & 3) << 5);
        Br[nq * 2 + n][ks] =
            *reinterpret_cast<const bf16x8*>(&Bs[slot][col * 64 + (cb >> 1)]);
      }
  };
  auto mfma_q = [&](int mq, int nq) {
    __builtin_amdgcn_s_setprio(1);
#pragma unroll
    for (int m = 0; m < 4; ++m)
#pragma unroll
      for (int n = 0; n < 2; ++n)
#pragma unroll
        for (int ks = 0; ks < 2; ++ks)
          acc[mq * 4 + m][nq * 2 + n] = MFMA16(
              Ar[m][ks], Br[nq * 2 + n][ks], acc[mq * 4 + m][nq * 2 + n], 0, 0, 0);
    __builtin_amdgcn_s_setprio(0);
  };

  // Prologue: K-tile 0 fully (slot0) + K-tile 1 A-half0 (slot1). 10 loads.
  stage_unit(0, 0); stage_unit(0, 1); stage_unit(0, 2); stage_unit(0, 3);
  stage_unit(1, 0);

  for (int it = 0; it < 24; ++it) {
    const int kt1 = 2 * it + 1;
    // p0: first read of slot0 (K-tile 2it) — vmcnt(4) covers its 8 loads.
    stage_unit(kt1, 1);
    VMCNT4(); BARRIER();
    loadA(0, 0); loadB(0, 0);
    mfma_q(0, 0);
    BARRIER();
    // p1
    stage_unit(kt1, 2);
    BARRIER();
    loadB(0, 1);
    mfma_q(0, 1);
    BARRIER();
    // p2: last slot0 reads
    stage_unit(kt1, 3);
    BARRIER();
    loadA(0, 1);
    mfma_q(1, 0);
    BARRIER();
    // p3: slot0 free -> stage next even tile
    stage_unit(kt1 + 1, 0);
    BARRIER();
    mfma_q(1, 1);
    BARRIER();
    // p4: first read of slot1 (K-tile 2it+1)
    stage_unit(kt1 + 1, 1);
    VMCNT4(); BARRIER();
    loadA(1, 0); loadB(1, 0);
    mfma_q(0, 0);
    BARRIER();
    // p5
    stage_unit(kt1 + 1, 2);
    BARRIER();
    loadB(1, 1);
    mfma_q(0, 1);
    BARRIER();
    // p6: last slot1 reads
    stage_unit(kt1 + 1, 3);
    BARRIER();
    loadA(1, 1);
    mfma_q(1, 0);
    BARRIER();
    // p7: slot1 free -> stage next odd tile's first unit
    stage_unit(kt1 + 2, 0);
    BARRIER();
    mfma_q(1, 1);
    BARRIER();
  }

#pragma unroll
  for (int m = 0; m < 8; ++m)
#pragma unroll
    for (int n = 0; n < 4; ++n)
#pragma unroll
      for (int reg = 0; reg < 4; ++reg) {
        const int gm = yt * 256 + wm * 128 + m * 16 + kg * 4 + reg;
        const int gn = xt * 256 + wn * 64 + n * 16 + lr;
        ushort h, l;
        splitf(acc[m][n][reg], h, l);
        Oh[(size_t)gm * 1024 + gn] = h;
        Ol[(size_t)gm * 1024 + gn] = l;
      }
}

// ---------------------------------------------------------------------------
// QK^T, bf16x2 split (3 MFMA), causal triangular grid, SPLIT-K halves.
// Flat grid 1088, chunked XCD swizzle. Packed tile output. No masking.
// ---------------------------------------------------------------------------
__global__ __launch_bounds__(256) void qk2(
    const ushort* __restrict__ q1h, const ushort* __restrict__ q1l,
    const ushort* __restrict__ k1h, const ushort* __restrict__ k1l,
    float* __restrict__ scoresA, float* __restrict__ scoresB) {
  __shared__ ushort Ahs[4096], Als[4096], Bhs[4096], Bls[4096];
  const int f = blockIdx.x;
  const int s = (f & 7) * 136 + (f >> 3);
  const int z = s / 544;
  const int rem = s % 544;
  const int b = rem / 136;
  int p = rem % 136, ti = 0, accp = 0;
  while (accp + ti + 1 <= p) { accp += ti + 1; ++ti; }
  const int tj = p - accp;
  const int tid = threadIdx.x, lane = tid & 63, w = tid >> 6;
  const int wr = w >> 1, wc = w & 1;
  const int lr = lane & 15, kg = lane >> 4;
  const int kh0 = z * 512;
  const ushort* qh = q1h + ((size_t)b * 2048 + ti * 128) * 1024 + kh0;
  const ushort* ql = q1l + ((size_t)b * 2048 + ti * 128) * 1024 + kh0;
  const ushort* kh = k1h + ((size_t)b * 2048 + tj * 128) * 1024 + kh0;
  const ushort* kl = k1l + ((size_t)b * 2048 + tj * 128) * 1024 + kh0;
  f32x4 acc[4][4] = {};

  for (int k0 = 0; k0 < 512; k0 += 32) {
    stage_bf16_32(qh + k0, 1024, Ahs, w, lane);
    stage_bf16_32(ql + k0, 1024, Als, w, lane);
    stage_bf16_32(kh + k0, 1024, Bhs, w, lane);
    stage_bf16_32(kl + k0, 1024, Bls, w, lane);
    __syncthreads();
    bf16x8 ah[4], al[4], bh[4], bl[4];
#pragma unroll
    for (int m = 0; m < 4; ++m) {
      ah[m] = *reinterpret_cast<bf16x8*>(&Ahs[(wr * 64 + m * 16 + lr) * 32 + kg * 8]);
      al[m] = *reinterpret_cast<bf16x8*>(&Als[(wr * 64 + m * 16 + lr) * 32 + kg * 8]);
    }
#pragma unroll
    for (int n = 0; n < 4; ++n) {
      bh[n] = *reinterpret_cast<bf16x8*>(&Bhs[(wc * 64 + n * 16 + lr) * 32 + kg * 8]);
      bl[n] = *reinterpret_cast<bf16x8*>(&Bls[(wc * 64 + n * 16 + lr) * 32 + kg * 8]);
    }
#pragma unroll
    for (int m = 0; m < 4; ++m)
#pragma unroll
      for (int n = 0; n < 4; ++n) {
        acc[m][n] = MFMA16(ah[m], bh[n], acc[m][n], 0, 0, 0);
        acc[m][n] = MFMA16(ah[m], bl[n], acc[m][n], 0, 0, 0);
        acc[m][n] = MFMA16(al[m], bh[n], acc[m][n], 0, 0, 0);
      }
    __syncthreads();
  }
  const float sc = 0.03125f;
  float* st = (z ? scoresB : scoresA) + ((size_t)b * 136 + p) * 16384;
#pragma unroll
  for (int m = 0; m < 4; ++m)
#pragma unroll
    for (int n = 0; n < 4; ++n)
#pragma unroll
      for (int reg = 0; reg < 4; ++reg) {
        const int il = wr * 64 + m * 16 + kg * 4 + reg;
        const int jl = wc * 64 + n * 16 + lr;
        st[il * 128 + jl] = acc[m][n][reg] * sc;
      }
}

// ---------------------------------------------------------------------------
// Merged: f < 8192 -> row softmax; f >= 8192 -> proj_v.
// ---------------------------------------------------------------------------
__global__ __launch_bounds__(256) void sm_projv(
    float* __restrict__ scoresA, const float* __restrict__ scoresB,
    const ushort* __restrict__ Wvt, const float* __restrict__ V,
    ushort* __restrict__ v1t) {
  __shared__ __align__(16) char smem[24576];
  const int tid = threadIdx.x, lane = tid & 63, w = tid >> 6;
  const int fg = blockIdx.x;
  if (fg < 8192) {
    float* red = reinterpret_cast<float*>(smem);
    const int b = fg >> 11, r = fg & 2047;
    const int ti = r >> 7, rl = r & 127, ncol = (ti + 1) * 128;
    const int valid = r + 1;
    const size_t tbase = ((size_t)b * 136 + (ti * (ti + 1)) / 2) * 16384;
    float* srowA = scoresA + tbase;
    const float* srowB = scoresB + tbase;

    float vals[2][4];
    float mx = -FLT_MAX;
#pragma unroll
    for (int c = 0; c < 2; ++c) {
      const int j = tid * 4 + c * 1024;
      const size_t o = (size_t)(j >> 7) * 16384 + rl * 128 + (j & 127);
      const float4 a = *reinterpret_cast<const float4*>(srowA + o);
      const float4 bb = *reinterpret_cast<const float4*>(srowB + o);
      vals[c][0] = (j + 0 < valid) ? a.x + bb.x : -FLT_MAX;
      vals[c][1] = (j + 1 < valid) ? a.y + bb.y : -FLT_MAX;
      vals[c][2] = (j + 2 < valid) ? a.z + bb.z : -FLT_MAX;
      vals[c][3] = (j + 3 < valid) ? a.w + bb.w : -FLT_MAX;
      mx = fmaxf(mx, fmaxf(fmaxf(vals[c][0], vals[c][1]),
                           fmaxf(vals[c][2], vals[c][3])));
    }
#pragma unroll
    for (int o = 32; o; o >>= 1) mx = fmaxf(mx, __shfl_xor(mx, o));
    if (lane == 0) red[w] = mx;
    __syncthreads();
    mx = fmaxf(fmaxf(red[0], red[1]), fmaxf(red[2], red[3]));

    float ex[2][4];
    float sum = 0.f;
#pragma unroll
    for (int c = 0; c < 2; ++c)
#pragma unroll
      for (int e = 0; e < 4; ++e) {
        const int j = tid * 4 + c * 1024 + e;
        ex[c][e] = (j < valid) ? __expf(vals[c][e] - mx) : 0.f;
        sum += ex[c][e];
      }
#pragma unroll
    for (int o = 32; o; o >>= 1) sum += __shfl_xor(sum, o);
    if (lane == 0) red[4 + w] = sum;
    __syncthreads();
    sum = red[4] + red[5] + red[6] + red[7];
    const float inv = 1.f / sum;
#pragma unroll
    for (int c = 0; c < 2; ++c) {
      const int j = tid * 4 + c * 1024;
      if (j < ncol) {
        ushort* pt =
            reinterpret_cast<ushort*>(srowA + (size_t)(j >> 7) * 16384);
        ushort4 pw;
        pw.x = f2bf(ex[c][0] * inv); pw.y = f2bf(ex[c][1] * inv);
        pw.z = f2bf(ex[c][2] * inv); pw.w = f2bf(ex[c][3] * inv);
        *reinterpret_cast<ushort4*>(&pt[rl * 256 + (j & 127)]) = pw;
      }
    }
  } else {
    ushort* Ahs = reinterpret_cast<ushort*>(smem);
    float* Bs = reinterpret_cast<float*>(smem + 8192);
    const int f2 = fg - 8192;
    const int yb = (f2 >> 3) & 7;
    const int xb = (f2 & 7) + ((f2 >> 6) << 3);
    const int wr = w >> 1, wc = w & 1;
    const int lr = lane & 15, kg = lane >> 4;
    const int m0 = yb * 128;
    const int n0 = xb * 128;
    f32x4 acc[4][4] = {};

    for (int k0 = 0; k0 < 1024; k0 += 32) {
      stage_bf16_32(Wvt + (size_t)m0 * 1024 + k0, 1024, Ahs, w, lane);
      stage_f32_32(V + (size_t)n0 * 1024 + k0, 1024, Bs, w, lane);
      __syncthreads();
      bf16x8 ah[4], bh[4];
#pragma unroll
      for (int m = 0; m < 4; ++m)
        ah[m] = *reinterpret_cast<bf16x8*>(
            &Ahs[(wr * 64 + m * 16 + lr) * 32 + kg * 8]);
#pragma unroll
      for (int n = 0; n < 4; ++n)
        bh[n] = cvt8(&Bs[(wc * 64 + n * 16 + lr) * 32 + kg * 8]);
#pragma unroll
      for (int m = 0; m < 4; ++m)
#pragma unroll
        for (int n = 0; n < 4; ++n)
          acc[m][n] = MFMA16(ah[m], bh[n], acc[m][n], 0, 0, 0);
      __syncthreads();
    }
#pragma unroll
    for (int m = 0; m < 4; ++m)
#pragma unroll
      for (int n = 0; n < 4; ++n)
#pragma unroll
        for (int reg = 0; reg < 4; ++reg) {
          const int gm = m0 + wr * 64 + m * 16 + kg * 4 + reg;
          const int gn = n0 + wc * 64 + n * 16 + lr;
          const int b = gn >> 11, jj = gn & 2047;
          v1t[((size_t)b << 21) + (size_t)gm * 2048 + jj] = f2bf(acc[m][n][reg]);
        }
  }
}

// ---------------------------------------------------------------------------
// PV: out = P @ v1. 128x64 tile (1024 blocks, 4/CU), chunked XCD swizzle.
// ---------------------------------------------------------------------------
__global__ __launch_bounds__(256) void pv2(const float* __restrict__ scores,
                                           const ushort* __restrict__ v1t,
                                           float* __restrict__ out) {
  __shared__ ushort Ps[128 * 64], Vs[64 * 64];
  const int fl = blockIdx.x;
  const int s = (fl & 7) * 128 + (fl >> 3);
  const int b = s >> 8, rem = s & 255;
  const int ti = 15 - (rem >> 4);
  const int n0 = (rem & 15) * 64;
  const int tid = threadIdx.x, lane = tid & 63, w = tid >> 6;
  const int wr = w >> 1, wc = w & 1;
  const int lr = lane & 15, kg = lane >> 4;
  const int tri_ti = (ti * (ti + 1)) / 2;
  const ushort* vbase = v1t + ((size_t)b << 21) + (size_t)n0 * 2048;
  const int kend = (ti + 1) * 128;
  f32x4 acc[4][2] = {};

  for (int k0 = 0; k0 < kend; k0 += 64) {
    const ushort* pt = reinterpret_cast<const ushort*>(
        scores + ((size_t)b * 136 + tri_ti + (k0 >> 7)) * 16384);
    stage_bf16_64(pt + (k0 & 64), 256, Ps, w, lane);
    stage_bf16_64x64(vbase + k0, 2048, Vs, w, lane);
    __syncthreads();
#pragma unroll
    for (int t2 = 0; t2 < 2; ++t2) {
      bf16x8 pa[4], vb[2];
#pragma unroll
      for (int m = 0; m < 4; ++m)
        pa[m] = *reinterpret_cast<bf16x8*>(
            &Ps[(wr * 64 + m * 16 + lr) * 64 + t2 * 32 + kg * 8]);
#pragma unroll
      for (int n = 0; n < 2; ++n)
        vb[n] = *reinterpret_cast<bf16x8*>(
            &Vs[(wc * 32 + n * 16 + lr) * 64 + t2 * 32 + kg * 8]);
#pragma unroll
      for (int m = 0; m < 4; ++m)
#pragma unroll
        for (int n = 0; n < 2; ++n)
          acc[m][n] = MFMA16(pa[m], vb[n], acc[m][n], 0, 0, 0);
    }
    __syncthreads();
  }
#pragma unroll
  for (int m = 0; m < 4; ++m)
#pragma unroll
    for (int n = 0; n < 2; ++n)
#pragma unroll
      for (int reg = 0; reg < 4; ++reg) {
        const int gm = ti * 128 + wr * 64 + m * 16 + kg * 4 + reg;
        const int gn = n0 + wc * 32 + n * 16 + lr;
        out[((size_t)b * 2048 + gm) * 1024 + gn] = acc[m][n][reg];
      }
}

extern "C" void kernel_launch(void* const* d_in, const int* in_sizes, int n_in,
                              void* d_out, int out_size, void* d_ws,
                              size_t ws_size, hipStream_t stream) {
  const float* q = (const float*)d_in[0];
  const float* k = (const float*)d_in[1];
  const float* v = (const float*)d_in[2];
  const float* Wq = (const float*)d_in[4];
  const float* Wk = (const float*)d_in[5];
  const float* Wv = (const float*)d_in[6];
  float* out = (float*)d_out;

  char* ws = (char*)d_ws;
  const size_t SCORES_T = 35651584;  // 4*136*16384*4
  float* scoresA = (float*)ws;
  float* scoresB = (float*)(ws + SCORES_T);
  ushort* qsh = (ushort*)ws;
  ushort* qsl = qsh + 8388608;
  ushort* ksh = qsh + 2 * 8388608;
  ushort* ksl = qsh + 3 * 8388608;
  ushort* q1hi = (ushort*)(ws + 2 * SCORES_T);
  ushort* q1lo = q1hi + 8388608;
  ushort* k1hi = q1hi + 2 * 8388608;
  ushort* k1lo = q1hi + 3 * 8388608;
  ushort* v1t = (ushort*)(ws + 2 * SCORES_T);
  ushort* Wqth = (ushort*)(ws + 2 * SCORES_T + 67108864);
  ushort* Wqtl = Wqth + 1048576;
  ushort* Wkth = Wqth + 2097152;
  ushort* Wktl = Wqth + 3145728;
  ushort* Wvt  = Wqth + 4194304;
  const size_t need = 2 * SCORES_T + 67108864 + 10485760;
  if (ws_size < need) return;

  dim3 blk(256);
  wt_split<<<dim3(7168), blk, 0, stream>>>(q, k, Wq, Wk, Wv, Wqth, Wqtl, Wkth,
                                           Wktl, Wvt, qsh, qsl, ksh, ksl);
  proj_qk8<<<dim3(256), dim3(512), 0, stream>>>(qsh, qsl, ksh, ksl, Wqth,
                                                Wqtl, Wkth, Wktl, q1hi, q1lo,
                                                k1hi, k1lo);
  qk2<<<dim3(1088), blk, 0, stream>>>(q1hi, q1lo, k1hi, k1lo, scoresA,
                                      scoresB);
  sm_projv<<<dim3(8704), blk, 0, stream>>>(scoresA, scoresB, Wvt, v, v1t);
  pv2<<<dim3(1024), blk, 0, stream>>>(scoresA, v1t, out);
}

// Round 10
// 308.669 us; speedup vs baseline: 1.0257x; 1.0257x over previous
//
#include <hip/hip_runtime.h>
#include <hip/hip_bf16.h>
#include <float.h>

// B=4, S=2048, D=1024 causal attention with input projections.
// out = softmax(mask((q@Wq)(k@Wk)^T / 32)) @ (v@Wv)
//
// Numerics: logits std ~342 -> q/k path uses bf16x2 (hi/lo RTN) split
// arithmetic, ~2^-18 effective. RTN mandatory (R2 lesson). v path bf16.
//
// R10: proj_qk8 restructured. R9's 8-phase port was latency-exposed (last
// staging unit issued 1 phase before its vmcnt -> ~700cyc exposed/tile) and
// its swizzle only cut conflicts to 4-way. Now: per K-tile {stage ALL of
// tile T+1 (8 loads); vmcnt(8) (T+1 stays in flight -> no drain); barrier;
// 24 ds_read + 64 MFMA compiler-scheduled; barrier}. Swizzle = G4's
// byte ^= (row&7)<<4 both sides (2-way = free). Everything else = R8/R9.

typedef __attribute__((ext_vector_type(8))) short bf16x8;
typedef __attribute__((ext_vector_type(4))) float f32x4;

#define MFMA16 __builtin_amdgcn_mfma_f32_16x16x32_bf16

union U8 { bf16x8 v; unsigned w[4]; };

__device__ __forceinline__ ushort f2bf(float x) {
  union { float f; unsigned u; } v; v.f = x;
  unsigned r = v.u + 0x7fffu + ((v.u >> 16) & 1u);
  return (ushort)(r >> 16);
}
__device__ __forceinline__ float bf2f(ushort h) {
  union { unsigned u; float f; } v; v.u = ((unsigned)h) << 16;
  return v.f;
}
__device__ __forceinline__ void splitf(float x, ushort& hi, ushort& lo) {
  hi = f2bf(x);
  lo = f2bf(x - bf2f(hi));
}

__device__ __forceinline__ bf16x8 cvt8(const float* lp) {
  U8 H;
#pragma unroll
  for (int p = 0; p < 4; ++p) {
    const unsigned u0 = __float_as_uint(lp[2 * p]);
    const unsigned u1 = __float_as_uint(lp[2 * p + 1]);
    const unsigned r0 = (u0 + 0x7fffu + ((u0 >> 16) & 1u)) >> 16;
    const unsigned r1 = (u1 + 0x7fffu + ((u1 >> 16) & 1u)) & 0xffff0000u;
    H.w[p] = r0 | r1;
  }
  return H.v;
}

#define GLOAD16(gp, lp)                                                        \
  __builtin_amdgcn_global_load_lds(                                            \
      (const __attribute__((address_space(1))) void*)(gp),                     \
      (__attribute__((address_space(3))) void*)(lp), 16, 0, 0)

#define BARRIER() asm volatile("s_barrier" ::: "memory")
#define VMCNT8() asm volatile("s_waitcnt vmcnt(8)" ::: "memory")

// bf16 slab 128 x 32 (8 KB, 8 chunks)
__device__ __forceinline__ void stage_bf16_32(const ushort* g, int pitch,
                                              ushort* lds, int w, int lane) {
#pragma unroll
  for (int i = 0; i < 2; ++i) {
    const int c = w * 2 + i;
    const int row = c * 16 + (lane >> 2);
    const int kp = (lane & 3) * 8;
    GLOAD16(g + (size_t)row * pitch + kp, lds + c * 512);
  }
}
// bf16 slab 128 x 64 (16 KB, 16 chunks)
__device__ __forceinline__ void stage_bf16_64(const ushort* g, int pitch,
                                              ushort* lds, int w, int lane) {
#pragma unroll
  for (int i = 0; i < 4; ++i) {
    const int c = w * 4 + i;
    const int row = c * 8 + (lane >> 3);
    const int kp = (lane & 7) * 8;
    GLOAD16(g + (size_t)row * pitch + kp, lds + c * 512);
  }
}
// bf16 slab 64 x 64 (8 KB, 8 chunks)
__device__ __forceinline__ void stage_bf16_64x64(const ushort* g, int pitch,
                                                 ushort* lds, int w, int lane) {
#pragma unroll
  for (int i = 0; i < 2; ++i) {
    const int c = w * 2 + i;
    const int row = c * 8 + (lane >> 3);
    const int kp = (lane & 7) * 8;
    GLOAD16(g + (size_t)row * pitch + kp, lds + c * 512);
  }
}
// fp32 slab 128 x 32 (16 KB, 16 chunks)
__device__ __forceinline__ void stage_f32_32(const float* g, int pitch,
                                             float* lds, int w, int lane) {
#pragma unroll
  for (int i = 0; i < 4; ++i) {
    const int c = w * 4 + i;
    const int row = c * 8 + (lane >> 3);
    const int kp = (lane & 7) * 4;
    GLOAD16(g + (size_t)row * pitch + kp, lds + c * 256);
  }
}

// Half-tile stage for proj_qk8: 128 rows x 64 cols bf16 (16 KB). Linear LDS
// dest; G4 swizzle byte ^= (row&7)<<4 realized by XORing the SOURCE column
// (rule #21: inverse-swz source + swz read, same involution).
__device__ __forceinline__ void stage_half8(const ushort* __restrict__ g,
                                            ushort* lds, int k0, int t) {
#pragma unroll
  for (int i = 0; i < 2; ++i) {
    const int c = t + i * 512;
    const int row = c >> 3;
    const int pcb = (c & 7) * 16;
    const int lcb = pcb ^ ((row & 7) << 4);
    GLOAD16(g + (size_t)row * 1024 + k0 + (lcb >> 1), lds + c * 8);
  }
}

// ---------------------------------------------------------------------------
// Merged prepass: f < 3072 -> W transpose+convert; f >= 3072 -> q/k split.
// ---------------------------------------------------------------------------
__global__ __launch_bounds__(256) void wt_split(
    const float* __restrict__ q, const float* __restrict__ k,
    const float* __restrict__ W0, const float* __restrict__ W1,
    const float* __restrict__ W2, ushort* __restrict__ Th0,
    ushort* __restrict__ Tl0, ushort* __restrict__ Th1,
    ushort* __restrict__ Tl1, ushort* __restrict__ Th2,
    ushort* __restrict__ qh, ushort* __restrict__ ql,
    ushort* __restrict__ kh, ushort* __restrict__ kl) {
  __shared__ float t[32][33];
  const int f = blockIdx.x;
  if (f < 3072) {
    const int z = f >> 10, r10 = f & 1023;
    const int bx = r10 & 31, by = r10 >> 5;
    const float* W = z == 0 ? W0 : (z == 1 ? W1 : W2);
    ushort* Th = z == 0 ? Th0 : (z == 1 ? Th1 : Th2);
    ushort* Tl = z == 0 ? Tl0 : (z == 1 ? Tl1 : nullptr);
    const int r = threadIdx.x >> 3, c4 = (threadIdx.x & 7) * 4;
    const float4 x = *reinterpret_cast<const float4*>(
        &W[(size_t)(bx * 32 + r) * 1024 + by * 32 + c4]);
    t[r][c4] = x.x; t[r][c4 + 1] = x.y; t[r][c4 + 2] = x.z; t[r][c4 + 3] = x.w;
    __syncthreads();
    ushort h[4], l[4];
#pragma unroll
    for (int j = 0; j < 4; ++j) splitf(t[c4 + j][r], h[j], l[j]);
    const size_t o = (size_t)(by * 32 + r) * 1024 + bx * 32 + c4;
    *reinterpret_cast<ushort4*>(&Th[o]) = ushort4{h[0], h[1], h[2], h[3]};
    if (Tl)
      *reinterpret_cast<ushort4*>(&Tl[o]) = ushort4{l[0], l[1], l[2], l[3]};
  } else {
    const int fl = f - 3072;
    const float* X = (fl >> 11) ? k : q;
    ushort* H = (fl >> 11) ? kh : qh;
    ushort* L = (fl >> 11) ? kl : ql;
    const int n4 = 2097152;
    for (int i = (fl & 2047) * 256 + threadIdx.x; i < n4; i += 2048 * 256) {
      const float4 x = reinterpret_cast<const float4*>(X)[i];
      ushort h0, l0, h1, l1, h2, l2, h3, l3;
      splitf(x.x, h0, l0); splitf(x.y, h1, l1);
      splitf(x.z, h2, l2); splitf(x.w, h3, l3);
      reinterpret_cast<ushort4*>(H)[i] = ushort4{h0, h1, h2, h3};
      reinterpret_cast<ushort4*>(L)[i] = ushort4{l0, l1, l2, l3};
    }
  }
}

// ---------------------------------------------------------------------------
// proj_qk8: O = A @ Wt^T as one bf16 GEMM, K' = 3072 segments
// [Ah.Bh | Al.Bh | Ah.Bl]. 256x256 tile, BK=64, 8 waves (2Mx4N).
// Per K-tile: stage ALL of tile T+1; vmcnt(8); barrier; body; barrier.
// 2 LDS slots (slot = kt&1, 128 KB). Grid 256, chunked XCD swizzle.
// ---------------------------------------------------------------------------
__global__ __launch_bounds__(512, 2) void proj_qk8(
    const ushort* __restrict__ Ah0, const ushort* __restrict__ Al0,
    const ushort* __restrict__ Ah1, const ushort* __restrict__ Al1,
    const ushort* __restrict__ Bh0, const ushort* __restrict__ Bl0,
    const ushort* __restrict__ Bh1, const ushort* __restrict__ Bl1,
    ushort* __restrict__ Oh0, ushort* __restrict__ Ol0,
    ushort* __restrict__ Oh1, ushort* __restrict__ Ol1) {
  __shared__ ushort As[2][16384];  // [slot][256 rows x 64 cols], 64 KB
  __shared__ ushort Bs[2][16384];  // 64 KB
  const int bid = blockIdx.x;
  const int fid = (bid & 7) * 32 + (bid >> 3);  // 256 blocks, 8 XCDs: chunked
  const int z = fid >> 7, r = fid & 127;
  const int yt = r >> 2, xt = r & 3;
  const ushort* Ah = z ? Ah1 : Ah0;
  const ushort* Al = z ? Al1 : Al0;
  const ushort* Bh = z ? Bh1 : Bh0;
  const ushort* Bl = z ? Bl1 : Bl0;
  ushort* Oh = z ? Oh1 : Oh0;
  ushort* Ol = z ? Ol1 : Ol0;
  const size_t am0 = (size_t)yt * 256 * 1024;
  const size_t bn0 = (size_t)xt * 256 * 1024;
  const int t = threadIdx.x;
  const int lane = t & 63, w = t >> 6;
  const int wm = w >> 2, wn = w & 3;
  const int lr = lane & 15, kg = lane >> 4;
  f32x4 acc[8][4] = {};
  bf16x8 Ar[4][2], Br[4][2];

  // Stage the FULL K-tile kt (4 units = 8 loads/thread).
  auto stage_tile = [&](int kt) {
    if (kt >= 48) kt -= 48;  // wrap: harmless dummy re-stage (uniform vmcnt)
    const int seg = kt >> 4;
    const int k0 = (kt & 15) * 64;
    const int slot = kt & 1;
    const ushort* ga = (seg == 1) ? Al : Ah;
    const ushort* gb = (seg == 2) ? Bl : Bh;
#pragma unroll
    for (int h = 0; h < 2; ++h)
      stage_half8(ga + am0 + (size_t)(h * 128) * 1024, &As[slot][h * 8192], k0, t);
#pragma unroll
    for (int h = 0; h < 2; ++h)
      stage_half8(gb + bn0 + (size_t)(h * 128) * 1024, &Bs[slot][h * 8192], k0, t);
  };
  auto loadA = [&](int slot, int mq) {
#pragma unroll
    for (int m = 0; m < 4; ++m)
#pragma unroll
      for (int ks = 0; ks < 2; ++ks) {
        const int row = wm * 128 + (mq * 4 + m) * 16 + lr;
        const int cb = (ks * 64 + kg * 16) ^ ((row & 7) << 4);
        Ar[m][ks] =
            *reinterpret_cast<const bf16x8*>(&As[slot][row * 64 + (cb >> 1)]);
      }
  };
  auto loadB = [&](int slot, int nq) {
#pragma unroll
    for (int n = 0; n < 2; ++n)
#pragma unroll
      for (int ks = 0; ks < 2; ++ks) {
        const int col = wn * 64 + (nq * 2 + n) * 16 + lr;
        const int cb = (ks * 64 + kg * 16) ^ ((col & 7) << 4);
        Br[nq * 2 + n][ks] =
            *reinterpret_cast<const bf16x8*>(&Bs[slot][col * 64 + (cb >> 1)]);
      }
  };
  auto mfma_q = [&](int mq, int nq) {
    __builtin_amdgcn_s_setprio(1);
#pragma unroll
    for (int m = 0; m < 4; ++m)
#pragma unroll
      for (int n = 0; n < 2; ++n)
#pragma unroll
        for (int ks = 0; ks < 2; ++ks)
          acc[mq * 4 + m][nq * 2 + n] = MFMA16(
              Ar[m][ks], Br[nq * 2 + n][ks], acc[mq * 4 + m][nq * 2 + n], 0, 0, 0);
    __builtin_amdgcn_s_setprio(0);
  };

  // Prologue: stage K-tile 0.
  stage_tile(0);
#pragma unroll 2
  for (int kt = 0; kt < 48; ++kt) {
    const int slot = kt & 1;
    stage_tile(kt + 1);   // 8 loads -> stay in flight across both barriers
    VMCNT8();             // drain only tile kt's 8 loads
    BARRIER();
    loadA(slot, 0); loadB(slot, 0);
    mfma_q(0, 0);
    loadB(slot, 1);
    mfma_q(0, 1);
    loadA(slot, 1);
    mfma_q(1, 0);
    mfma_q(1, 1);
    BARRIER();
  }

#pragma unroll
  for (int m = 0; m < 8; ++m)
#pragma unroll
    for (int n = 0; n < 4; ++n)
#pragma unroll
      for (int reg = 0; reg < 4; ++reg) {
        const int gm = yt * 256 + wm * 128 + m * 16 + kg * 4 + reg;
        const int gn = xt * 256 + wn * 64 + n * 16 + lr;
        ushort h, l;
        splitf(acc[m][n][reg], h, l);
        Oh[(size_t)gm * 1024 + gn] = h;
        Ol[(size_t)gm * 1024 + gn] = l;
      }
}

// ---------------------------------------------------------------------------
// QK^T, bf16x2 split (3 MFMA), causal triangular grid, SPLIT-K halves.
// Flat grid 1088, chunked XCD swizzle. Packed tile output. No masking.
// ---------------------------------------------------------------------------
__global__ __launch_bounds__(256) void qk2(
    const ushort* __restrict__ q1h, const ushort* __restrict__ q1l,
    const ushort* __restrict__ k1h, const ushort* __restrict__ k1l,
    float* __restrict__ scoresA, float* __restrict__ scoresB) {
  __shared__ ushort Ahs[4096], Als[4096], Bhs[4096], Bls[4096];
  const int f = blockIdx.x;
  const int s = (f & 7) * 136 + (f >> 3);
  const int z = s / 544;
  const int rem = s % 544;
  const int b = rem / 136;
  int p = rem % 136, ti = 0, accp = 0;
  while (accp + ti + 1 <= p) { accp += ti + 1; ++ti; }
  const int tj = p - accp;
  const int tid = threadIdx.x, lane = tid & 63, w = tid >> 6;
  const int wr = w >> 1, wc = w & 1;
  const int lr = lane & 15, kg = lane >> 4;
  const int kh0 = z * 512;
  const ushort* qh = q1h + ((size_t)b * 2048 + ti * 128) * 1024 + kh0;
  const ushort* ql = q1l + ((size_t)b * 2048 + ti * 128) * 1024 + kh0;
  const ushort* kh = k1h + ((size_t)b * 2048 + tj * 128) * 1024 + kh0;
  const ushort* kl = k1l + ((size_t)b * 2048 + tj * 128) * 1024 + kh0;
  f32x4 acc[4][4] = {};

  for (int k0 = 0; k0 < 512; k0 += 32) {
    stage_bf16_32(qh + k0, 1024, Ahs, w, lane);
    stage_bf16_32(ql + k0, 1024, Als, w, lane);
    stage_bf16_32(kh + k0, 1024, Bhs, w, lane);
    stage_bf16_32(kl + k0, 1024, Bls, w, lane);
    __syncthreads();
    bf16x8 ah[4], al[4], bh[4], bl[4];
#pragma unroll
    for (int m = 0; m < 4; ++m) {
      ah[m] = *reinterpret_cast<bf16x8*>(&Ahs[(wr * 64 + m * 16 + lr) * 32 + kg * 8]);
      al[m] = *reinterpret_cast<bf16x8*>(&Als[(wr * 64 + m * 16 + lr) * 32 + kg * 8]);
    }
#pragma unroll
    for (int n = 0; n < 4; ++n) {
      bh[n] = *reinterpret_cast<bf16x8*>(&Bhs[(wc * 64 + n * 16 + lr) * 32 + kg * 8]);
      bl[n] = *reinterpret_cast<bf16x8*>(&Bls[(wc * 64 + n * 16 + lr) * 32 + kg * 8]);
    }
#pragma unroll
    for (int m = 0; m < 4; ++m)
#pragma unroll
      for (int n = 0; n < 4; ++n) {
        acc[m][n] = MFMA16(ah[m], bh[n], acc[m][n], 0, 0, 0);
        acc[m][n] = MFMA16(ah[m], bl[n], acc[m][n], 0, 0, 0);
        acc[m][n] = MFMA16(al[m], bh[n], acc[m][n], 0, 0, 0);
      }
    __syncthreads();
  }
  const float sc = 0.03125f;
  float* st = (z ? scoresB : scoresA) + ((size_t)b * 136 + p) * 16384;
#pragma unroll
  for (int m = 0; m < 4; ++m)
#pragma unroll
    for (int n = 0; n < 4; ++n)
#pragma unroll
      for (int reg = 0; reg < 4; ++reg) {
        const int il = wr * 64 + m * 16 + kg * 4 + reg;
        const int jl = wc * 64 + n * 16 + lr;
        st[il * 128 + jl] = acc[m][n][reg] * sc;
      }
}

// ---------------------------------------------------------------------------
// Merged: f < 8192 -> row softmax; f >= 8192 -> proj_v.
// ---------------------------------------------------------------------------
__global__ __launch_bounds__(256) void sm_projv(
    float* __restrict__ scoresA, const float* __restrict__ scoresB,
    const ushort* __restrict__ Wvt, const float* __restrict__ V,
    ushort* __restrict__ v1t) {
  __shared__ __align__(16) char smem[24576];
  const int tid = threadIdx.x, lane = tid & 63, w = tid >> 6;
  const int fg = blockIdx.x;
  if (fg < 8192) {
    float* red = reinterpret_cast<float*>(smem);
    const int b = fg >> 11, r = fg & 2047;
    const int ti = r >> 7, rl = r & 127, ncol = (ti + 1) * 128;
    const int valid = r + 1;
    const size_t tbase = ((size_t)b * 136 + (ti * (ti + 1)) / 2) * 16384;
    float* srowA = scoresA + tbase;
    const float* srowB = scoresB + tbase;

    float vals[2][4];
    float mx = -FLT_MAX;
#pragma unroll
    for (int c = 0; c < 2; ++c) {
      const int j = tid * 4 + c * 1024;
      const size_t o = (size_t)(j >> 7) * 16384 + rl * 128 + (j & 127);
      const float4 a = *reinterpret_cast<const float4*>(srowA + o);
      const float4 bb = *reinterpret_cast<const float4*>(srowB + o);
      vals[c][0] = (j + 0 < valid) ? a.x + bb.x : -FLT_MAX;
      vals[c][1] = (j + 1 < valid) ? a.y + bb.y : -FLT_MAX;
      vals[c][2] = (j + 2 < valid) ? a.z + bb.z : -FLT_MAX;
      vals[c][3] = (j + 3 < valid) ? a.w + bb.w : -FLT_MAX;
      mx = fmaxf(mx, fmaxf(fmaxf(vals[c][0], vals[c][1]),
                           fmaxf(vals[c][2], vals[c][3])));
    }
#pragma unroll
    for (int o = 32; o; o >>= 1) mx = fmaxf(mx, __shfl_xor(mx, o));
    if (lane == 0) red[w] = mx;
    __syncthreads();
    mx = fmaxf(fmaxf(red[0], red[1]), fmaxf(red[2], red[3]));

    float ex[2][4];
    float sum = 0.f;
#pragma unroll
    for (int c = 0; c < 2; ++c)
#pragma unroll
      for (int e = 0; e < 4; ++e) {
        const int j = tid * 4 + c * 1024 + e;
        ex[c][e] = (j < valid) ? __expf(vals[c][e] - mx) : 0.f;
        sum += ex[c][e];
      }
#pragma unroll
    for (int o = 32; o; o >>= 1) sum += __shfl_xor(sum, o);
    if (lane == 0) red[4 + w] = sum;
    __syncthreads();
    sum = red[4] + red[5] + red[6] + red[7];
    const float inv = 1.f / sum;
#pragma unroll
    for (int c = 0; c < 2; ++c) {
      const int j = tid * 4 + c * 1024;
      if (j < ncol) {
        ushort* pt =
            reinterpret_cast<ushort*>(srowA + (size_t)(j >> 7) * 16384);
        ushort4 pw;
        pw.x = f2bf(ex[c][0] * inv); pw.y = f2bf(ex[c][1] * inv);
        pw.z = f2bf(ex[c][2] * inv); pw.w = f2bf(ex[c][3] * inv);
        *reinterpret_cast<ushort4*>(&pt[rl * 256 + (j & 127)]) = pw;
      }
    }
  } else {
    ushort* Ahs = reinterpret_cast<ushort*>(smem);
    float* Bs = reinterpret_cast<float*>(smem + 8192);
    const int f2 = fg - 8192;
    const int yb = (f2 >> 3) & 7;
    const int xb = (f2 & 7) + ((f2 >> 6) << 3);
    const int wr = w >> 1, wc = w & 1;
    const int lr = lane & 15, kg = lane >> 4;
    const int m0 = yb * 128;
    const int n0 = xb * 128;
    f32x4 acc[4][4] = {};

    for (int k0 = 0; k0 < 1024; k0 += 32) {
      stage_bf16_32(Wvt + (size_t)m0 * 1024 + k0, 1024, Ahs, w, lane);
      stage_f32_32(V + (size_t)n0 * 1024 + k0, 1024, Bs, w, lane);
      __syncthreads();
      bf16x8 ah[4], bh[4];
#pragma unroll
      for (int m = 0; m < 4; ++m)
        ah[m] = *reinterpret_cast<bf16x8*>(
            &Ahs[(wr * 64 + m * 16 + lr) * 32 + kg * 8]);
#pragma unroll
      for (int n = 0; n < 4; ++n)
        bh[n] = cvt8(&Bs[(wc * 64 + n * 16 + lr) * 32 + kg * 8]);
#pragma unroll
      for (int m = 0; m < 4; ++m)
#pragma unroll
        for (int n = 0; n < 4; ++n)
          acc[m][n] = MFMA16(ah[m], bh[n], acc[m][n], 0, 0, 0);
      __syncthreads();
    }
#pragma unroll
    for (int m = 0; m < 4; ++m)
#pragma unroll
      for (int n = 0; n < 4; ++n)
#pragma unroll
        for (int reg = 0; reg < 4; ++reg) {
          const int gm = m0 + wr * 64 + m * 16 + kg * 4 + reg;
          const int gn = n0 + wc * 64 + n * 16 + lr;
          const int b = gn >> 11, jj = gn & 2047;
          v1t[((size_t)b << 21) + (size_t)gm * 2048 + jj] = f2bf(acc[m][n][reg]);
        }
  }
}

// ---------------------------------------------------------------------------
// PV: out = P @ v1. 128x64 tile (1024 blocks, 4/CU), chunked XCD swizzle.
// ---------------------------------------------------------------------------
__global__ __launch_bounds__(256) void pv2(const float* __restrict__ scores,
                                           const ushort* __restrict__ v1t,
                                           float* __restrict__ out) {
  __shared__ ushort Ps[128 * 64], Vs[64 * 64];
  const int fl = blockIdx.x;
  const int s = (fl & 7) * 128 + (fl >> 3);
  const int b = s >> 8, rem = s & 255;
  const int ti = 15 - (rem >> 4);
  const int n0 = (rem & 15) * 64;
  const int tid = threadIdx.x, lane = tid & 63, w = tid >> 6;
  const int wr = w >> 1, wc = w & 1;
  const int lr = lane & 15, kg = lane >> 4;
  const int tri_ti = (ti * (ti + 1)) / 2;
  const ushort* vbase = v1t + ((size_t)b << 21) + (size_t)n0 * 2048;
  const int kend = (ti + 1) * 128;
  f32x4 acc[4][2] = {};

  for (int k0 = 0; k0 < kend; k0 += 64) {
    const ushort* pt = reinterpret_cast<const ushort*>(
        scores + ((size_t)b * 136 + tri_ti + (k0 >> 7)) * 16384);
    stage_bf16_64(pt + (k0 & 64), 256, Ps, w, lane);
    stage_bf16_64x64(vbase + k0, 2048, Vs, w, lane);
    __syncthreads();
#pragma unroll
    for (int t2 = 0; t2 < 2; ++t2) {
      bf16x8 pa[4], vb[2];
#pragma unroll
      for (int m = 0; m < 4; ++m)
        pa[m] = *reinterpret_cast<bf16x8*>(
            &Ps[(wr * 64 + m * 16 + lr) * 64 + t2 * 32 + kg * 8]);
#pragma unroll
      for (int n = 0; n < 2; ++n)
        vb[n] = *reinterpret_cast<bf16x8*>(
            &Vs[(wc * 32 + n * 16 + lr) * 64 + t2 * 32 + kg * 8]);
#pragma unroll
      for (int m = 0; m < 4; ++m)
#pragma unroll
        for (int n = 0; n < 2; ++n)
          acc[m][n] = MFMA16(pa[m], vb[n], acc[m][n], 0, 0, 0);
    }
    __syncthreads();
  }
#pragma unroll
  for (int m = 0; m < 4; ++m)
#pragma unroll
    for (int n = 0; n < 2; ++n)
#pragma unroll
      for (int reg = 0; reg < 4; ++reg) {
        const int gm = ti * 128 + wr * 64 + m * 16 + kg * 4 + reg;
        const int gn = n0 + wc * 32 + n * 16 + lr;
        out[((size_t)b * 2048 + gm) * 1024 + gn] = acc[m][n][reg];
      }
}

extern "C" void kernel_launch(void* const* d_in, const int* in_sizes, int n_in,
                              void* d_out, int out_size, void* d_ws,
                              size_t ws_size, hipStream_t stream) {
  const float* q = (const float*)d_in[0];
  const float* k = (const float*)d_in[1];
  const float* v = (const float*)d_in[2];
  const float* Wq = (const float*)d_in[4];
  const float* Wk = (const float*)d_in[5];
  const float* Wv = (const float*)d_in[6];
  float* out = (float*)d_out;

  char* ws = (char*)d_ws;
  const size_t SCORES_T = 35651584;  // 4*136*16384*4
  float* scoresA = (float*)ws;
  float* scoresB = (float*)(ws + SCORES_T);
  ushort* qsh = (ushort*)ws;
  ushort* qsl = qsh + 8388608;
  ushort* ksh = qsh + 2 * 8388608;
  ushort* ksl = qsh + 3 * 8388608;
  ushort* q1hi = (ushort*)(ws + 2 * SCORES_T);
  ushort* q1lo = q1hi + 8388608;
  ushort* k1hi = q1hi + 2 * 8388608;
  ushort* k1lo = q1hi + 3 * 8388608;
  ushort* v1t = (ushort*)(ws + 2 * SCORES_T);
  ushort* Wqth = (ushort*)(ws + 2 * SCORES_T + 67108864);
  ushort* Wqtl = Wqth + 1048576;
  ushort* Wkth = Wqth + 2097152;
  ushort* Wktl = Wqth + 3145728;
  ushort* Wvt  = Wqth + 4194304;
  const size_t need = 2 * SCORES_T + 67108864 + 10485760;
  if (ws_size < need) return;

  dim3 blk(256);
  wt_split<<<dim3(7168), blk, 0, stream>>>(q, k, Wq, Wk, Wv, Wqth, Wqtl, Wkth,
                                           Wktl, Wvt, qsh, qsl, ksh, ksl);
  proj_qk8<<<dim3(256), dim3(512), 0, stream>>>(qsh, qsl, ksh, ksl, Wqth,
                                                Wqtl, Wkth, Wktl, q1hi, q1lo,
                                                k1hi, k1lo);
  qk2<<<dim3(1088), blk, 0, stream>>>(q1hi, q1lo, k1hi, k1lo, scoresA,
                                      scoresB);
  sm_projv<<<dim3(8704), blk, 0, stream>>>(scoresA, scoresB, Wvt, v, v1t);
  pv2<<<dim3(1024), blk, 0, stream>>>(scoresA, v1t, out);
}